// Round 5
// baseline (378.258 us; speedup 1.0000x reference)
//
#include <hip/hip_runtime.h>
#include <math.h>

#define NROWS 65536
#define PER 64
#define BIMG 1024
#define NCLS 36
#define OBJ_DIM 192
#define EMB 200
#define POSD 128
#define HID 1024
#define EPSV 1e-5f

#define KP 384            // padded K for GEMM1 (355 real -> 384)
#define XSTR 392          // Xs LDS row stride (fp16 units)
#define GCSTR 136         // Gc row stride (fp16 units): 128 + 8
#define W2KP 1024         // W2T k stride
#define LSTR 52           // logit stash row stride (floats)

typedef __attribute__((ext_vector_type(8))) _Float16 f16x8;
typedef __attribute__((ext_vector_type(4))) _Float16 f16x4;
typedef __attribute__((ext_vector_type(4))) float f32x4;

// ---------------- prep A: copy/scale/convert parts of W1fT + W2T + bias ----------------
// W1fT[h][k]: k<192 -> dec1_W[k][h]; 227..354 -> dec1_W[k+165][h]; >=355 -> 0.
// (k in 192..226 is written by k_prep_embed.)  Scaled by bn1k scale sc[h].
__global__ __launch_bounds__(256) void k_prep_copy(
    const float* __restrict__ dec1_W, const float* __restrict__ dec1_b,
    const float* __restrict__ bn1k_g, const float* __restrict__ bn1k_b,
    const float* __restrict__ bn1k_m, const float* __restrict__ bn1k_v,
    const float* __restrict__ dec2_W,
    _Float16* __restrict__ W1fT, _Float16* __restrict__ W2T,
    float* __restrict__ bs)
{
    int idx = blockIdx.x * 256 + threadIdx.x;
    if (idx < HID * KP) {
        int h = idx / KP, k = idx % KP;
        if (k >= 192 && k < 227) return;    // embed kernel's region
        float sc = rsqrtf(bn1k_v[h] + EPSV) * bn1k_g[h];
        float v;
        if (k < 192) v = dec1_W[(size_t)k * HID + h];
        else if (k < 355) v = dec1_W[(size_t)(k - 227 + 392) * HID + h];
        else v = 0.f;
        W1fT[(size_t)h * KP + k] = (_Float16)(v * sc);
        if (k == 0) bs[h] = (dec1_b[h] - bn1k_m[h]) * sc + bn1k_b[h];
    } else {
        int j = idx - HID * KP;             // 48 * 1024 region
        if (j < 48 * W2KP) {
            int c = j / W2KP, h2 = j % W2KP;
            float v = (c < NCLS) ? dec2_W[(size_t)h2 * NCLS + c] : 0.f;
            W2T[j] = (_Float16)v;
        }
    }
}

// ---------------- prep B: embed fold  W1fT[h][192+e] = sum_j obj_embed_W[e][j]*dec1_W[192+j][h] ----
// 64 blocks x 256 threads; block owns 16 h columns; dec1_W tile staged in LDS.
__global__ __launch_bounds__(256) void k_prep_embed(
    const float* __restrict__ obj_embed_W, const float* __restrict__ dec1_W,
    const float* __restrict__ bn1k_g, const float* __restrict__ bn1k_v,
    _Float16* __restrict__ W1fT)
{
    __shared__ float A[EMB * 16];           // dec1_W[192:392][h0:h0+16]
    int t = threadIdx.x;
    int h0 = blockIdx.x * 16;
    for (int idx = t; idx < EMB * 16; idx += 256) {
        int j = idx >> 4, hh = idx & 15;
        A[idx] = dec1_W[(size_t)(192 + j) * HID + h0 + hh];
    }
    __syncthreads();
    int hh = t & 15;
    int h = h0 + hh;
    float sc = rsqrtf(bn1k_v[h] + EPSV) * bn1k_g[h];
    for (int e = t >> 4; e < 35; e += 16) {
        float acc = 0.f;
        for (int j = 0; j < EMB; ++j)
            acc = fmaf(obj_embed_W[e * EMB + j], A[j * 16 + hh], acc);
        W1fT[(size_t)h * KP + 192 + e] = (_Float16)(acc * sc);
    }
}

// ---------------- main fused kernel: 64 rows/block, 512 threads (8 waves), fp16 MFMA ----
__global__ __launch_bounds__(512, 4) void k_main(
    const float* __restrict__ distribution, const float* __restrict__ features,
    const float* __restrict__ boxes,
    const float* __restrict__ bn4_g, const float* __restrict__ bn4_b,
    const float* __restrict__ bn4_m, const float* __restrict__ bn4_v,
    const float* __restrict__ pos_W, const float* __restrict__ pos_b,
    const _Float16* __restrict__ W1fT, const _Float16* __restrict__ W2T,
    const float* __restrict__ bs, const float* __restrict__ dec2_b,
    float* __restrict__ out)
{
    extern __shared__ __align__(16) char smem[];
    _Float16* Xs = (_Float16*)smem;                 // 64*392 fp16 = 50176 B
    _Float16* Gc = (_Float16*)(smem + 50176);       // 64*136 fp16 = 17408 B
    float* LstA  = (float*)smem;                    // aliases Xs: 64*52*4 = 13312 B
    float* LstB  = LstA + 64 * LSTR;                // 13312 B (still inside Xs region)

    int t = threadIdx.x;
    int row0 = blockIdx.x * PER;

    // ---- stage X = [features | distribution | pos] as fp16, K padded to 384 ----
    {
        int r = t >> 3;            // 0..63 local row
        int ko = t & 7;            // k octant (48 each)
        int grow = row0 + r;
        const float* bx = boxes + (size_t)grow * 5;
        float x1 = bx[1], y1 = bx[2], x2 = bx[3], y2 = bx[4];
        float w = x2 - x1 + 1.f, hh = y2 - y1 + 1.f;
        float cs[4] = {x1 + 0.5f * w, y1 + 0.5f * hh, w, hh};
        float hv[4];
#pragma unroll
        for (int i = 0; i < 4; i++)
            hv[i] = (cs[i] - bn4_m[i]) * rsqrtf(bn4_v[i] + EPSV) * bn4_g[i] + bn4_b[i];
        for (int jb = 0; jb < 6; ++jb) {
            int kb = ko * 48 + jb * 8;
            f16x8 v8;
#pragma unroll
            for (int e = 0; e < 8; ++e) {
                int k = kb + e;
                float v;
                if (k < 192) v = features[(size_t)grow * OBJ_DIM + k];
                else if (k < 227) v = distribution[(size_t)grow * (NCLS - 1) + (k - 192)];
                else if (k < 355) {
                    int j = k - 227;
                    float p = pos_b[j];
                    p = fmaf(hv[0], pos_W[j], p);
                    p = fmaf(hv[1], pos_W[POSD + j], p);
                    p = fmaf(hv[2], pos_W[2 * POSD + j], p);
                    p = fmaf(hv[3], pos_W[3 * POSD + j], p);
                    v = fmaxf(p, 0.f);
                } else v = 0.f;
                v8[e] = (_Float16)v;
            }
            *(f16x8*)&Xs[r * XSTR + kb] = v8;
        }
    }
    __syncthreads();

    int wv = t >> 6, lane = t & 63, lr = lane & 15, lq = lane >> 4;
    int rg = wv & 3, kh = wv >> 2;     // GEMM2: row-group, K-half

    f32x4 Lg[3];                       // logit frags: rows 16rg..+15 x classes 48 (K-half kh)
#pragma unroll
    for (int n = 0; n < 3; n++) Lg[n] = (f32x4){0.f, 0.f, 0.f, 0.f};

    for (int c0 = 0; c0 < 2; ++c0) {   // hidden chunks of 512
        int H0 = c0 * 512;
        f32x4 C[4][4];
#pragma unroll
        for (int j = 0; j < 4; j++)
#pragma unroll
            for (int n = 0; n < 4; n++) C[j][n] = (f32x4){0.f, 0.f, 0.f, 0.f};

        // ---- GEMM1 K-loop (transposed: A=W1fT hidden rows, B=Xs rows); no barriers ----
        for (int ks = 0; ks < 12; ++ks) {
            int k0 = ks * 32 + lq * 8;
            f16x8 ah[4], bh[4];
#pragma unroll
            for (int j = 0; j < 4; j++)
                ah[j] = *(const f16x8*)(W1fT + (size_t)(H0 + 16 * (wv + 8 * j) + lr) * KP + k0);
#pragma unroll
            for (int n = 0; n < 4; n++)
                bh[n] = *(const f16x8*)&Xs[(16 * n + lr) * XSTR + k0];
#pragma unroll
            for (int j = 0; j < 4; j++)
#pragma unroll
                for (int n = 0; n < 4; n++)
                    C[j][n] = __builtin_amdgcn_mfma_f32_16x16x32_f16(ah[j], bh[n], C[j][n], 0, 0, 0);
        }

        // ---- transform + GEMM2, 4 sub-rounds of 128 hidden (8 waves x 16) ----
        for (int j = 0; j < 4; ++j) {
            __syncthreads();           // Gc free (previous sub-round's GEMM2 done)
            int hb = H0 + 128 * j + 16 * wv + 4 * lq;
            f32x4 bsv = *(const f32x4*)(bs + hb);
#pragma unroll
            for (int n = 0; n < 4; n++) {
                f16x4 g4;
#pragma unroll
                for (int e = 0; e < 4; ++e)
                    g4[e] = (_Float16)fmaxf(C[j][n][e] + bsv[e], 0.f);
                *(f16x4*)&Gc[(16 * n + lr) * GCSTR + 16 * wv + 4 * lq] = g4;
            }
            __syncthreads();           // Gc filled
#pragma unroll
            for (int ks2 = 0; ks2 < 2; ++ks2) {
                int kloc = kh * 64 + ks2 * 32 + lq * 8;
                f16x8 a2 = *(const f16x8*)&Gc[(16 * rg + lr) * GCSTR + kloc];
                int hg = H0 + 128 * j + kloc;
#pragma unroll
                for (int n = 0; n < 3; n++) {
                    f16x8 b2 = *(const f16x8*)(W2T + (size_t)(16 * n + lr) * W2KP + hg);
                    Lg[n] = __builtin_amdgcn_mfma_f32_16x16x32_f16(a2, b2, Lg[n], 0, 0, 0);
                }
            }
        }
    }

    // ---- stash logits: two K-half buffers (alias over dead Xs region) ----
    float* myL = kh ? LstB : LstA;
#pragma unroll
    for (int n = 0; n < 3; n++)
#pragma unroll
        for (int e = 0; e < 4; ++e)
            myL[(16 * rg + 4 * lq + e) * LSTR + 16 * n + lr] = Lg[n][e];
    __syncthreads();

    // ---- softmax head + fused per-image human argmax (wave 0) ----
    if (t < 64) {
        int row = row0 + t;
        float lg[36];
#pragma unroll
        for (int c = 1; c < 36; ++c)
            lg[c] = LstA[t * LSTR + c] + LstB[t * LSTR + c] + dec2_b[c];
        float m = lg[1];
#pragma unroll
        for (int c = 2; c < 36; ++c) m = fmaxf(m, lg[c]);
        float d[35];
        float s = 0.f;
#pragma unroll
        for (int c = 1; c < 36; ++c) { float e = expf(lg[c] - m); d[c - 1] = e; s += e; }
        float inv = 1.0f / s;
        float* dout = out + (size_t)row * 35;
#pragma unroll
        for (int j = 0; j < 35; ++j) dout[j] = d[j] * inv;

        // per-row argmax over dist cols 1..34 (first-occurrence), label = distcol+1
        float best = -1.f; int bi = 1;
#pragma unroll
        for (int c = 1; c < 35; ++c) {
            float v = d[c] * inv;
            if (v > best) { best = v; bi = c; }
        }

        // block == image: argmax over dist[:,0] across the 64 lanes
        float v0 = d[0] * inv;
        float mv = v0; int mi = t;
#pragma unroll
        for (int off = 32; off > 0; off >>= 1) {
            float ov = __shfl_down(mv, off);
            int   oi = __shfl_down(mi, off);
            if (ov > mv || (ov == mv && oi < mi)) { mv = ov; mi = oi; }
        }
        int human = __shfl(mi, 0);     // local row of the human
        bool isH = (t == human);
        out[(size_t)NROWS * 35 + row] = isH ? v0 : best;
        out[(size_t)NROWS * 36 + row] = isH ? 1.0f : (float)(bi + 1);
        if (t == 0) out[(size_t)NROWS * 37 + blockIdx.x] = (float)(row0 + human);
    }
}

extern "C" void kernel_launch(void* const* d_in, const int* in_sizes, int n_in,
                              void* d_out, int out_size, void* d_ws, size_t ws_size,
                              hipStream_t stream)
{
    (void)in_sizes; (void)n_in; (void)out_size; (void)ws_size;
    const float* distribution = (const float*)d_in[0];
    const float* features     = (const float*)d_in[1];
    const float* boxes        = (const float*)d_in[2];
    const float* obj_embed_W  = (const float*)d_in[3];
    const float* bn4_g        = (const float*)d_in[4];
    const float* bn4_b        = (const float*)d_in[5];
    const float* bn4_m        = (const float*)d_in[6];
    const float* bn4_v        = (const float*)d_in[7];
    const float* pos_W        = (const float*)d_in[8];
    const float* pos_b        = (const float*)d_in[9];
    const float* dec1_W       = (const float*)d_in[10];
    const float* dec1_b       = (const float*)d_in[11];
    const float* bn1k_g       = (const float*)d_in[12];
    const float* bn1k_b       = (const float*)d_in[13];
    const float* bn1k_m       = (const float*)d_in[14];
    const float* bn1k_v       = (const float*)d_in[15];
    const float* dec2_W       = (const float*)d_in[16];
    const float* dec2_b       = (const float*)d_in[17];

    float* out = (float*)d_out;

    // ws layout (~0.9 MB)
    _Float16* W1fT = (_Float16*)d_ws;                      // 1024*384
    _Float16* W2T  = W1fT + (size_t)HID * KP;              // 48*1024
    float*    bsv  = (float*)(W2T + (size_t)48 * W2KP);    // 1024

    const int LDS_BYTES = 50176 + 17408;                   // 67584
    hipFuncSetAttribute((const void*)k_main,
                        hipFuncAttributeMaxDynamicSharedMemorySize, LDS_BYTES);

    int prep_elems = HID * KP + 48 * W2KP;
    k_prep_copy<<<(prep_elems + 255) / 256, 256, 0, stream>>>(
        dec1_W, dec1_b, bn1k_g, bn1k_b, bn1k_m, bn1k_v, dec2_W, W1fT, W2T, bsv);
    k_prep_embed<<<64, 256, 0, stream>>>(obj_embed_W, dec1_W, bn1k_g, bn1k_v, W1fT);

    k_main<<<BIMG, 512, LDS_BYTES, stream>>>(
        distribution, features, boxes, bn4_g, bn4_b, bn4_m, bn4_v, pos_W, pos_b,
        W1fT, W2T, bsv, dec2_b, out);
}

// Round 6
// 359.398 us; speedup vs baseline: 1.0525x; 1.0525x over previous
//
#include <hip/hip_runtime.h>
#include <math.h>

#define NROWS 65536
#define PER 64
#define BIMG 1024
#define NCLS 36
#define OBJ_DIM 192
#define EMB 200
#define POSD 128
#define HID 1024
#define EPSV 1e-5f

#define KP 384            // padded K for GEMM1 (355 real -> 384)
#define XSTR 392          // Xs LDS row stride (fp16 units)
#define GCSTR 136         // Gc row stride (fp16 units): 128 + 8
#define W2KP 1024         // W2T k stride
#define LSTR 52           // logit stash row stride (floats)

typedef __attribute__((ext_vector_type(8))) _Float16 f16x8;
typedef __attribute__((ext_vector_type(4))) _Float16 f16x4;
typedef __attribute__((ext_vector_type(4))) float f32x4;

// ---------------- merged prep ----------------
// blocks 0..63: embed fold  W1fT[h][192+e] = sc[h] * sum_j obj_embed_W[e][j]*dec1_W[192+j][h]
// blocks 64..1599: k-major coalesced copy of W1fT (k<192, 227..383)  + bias (k==0)
// blocks 1600..1791: W2T
__global__ __launch_bounds__(256) void k_prep(
    const float* __restrict__ obj_embed_W, const float* __restrict__ dec1_W,
    const float* __restrict__ dec1_b,
    const float* __restrict__ bn1k_g, const float* __restrict__ bn1k_b,
    const float* __restrict__ bn1k_m, const float* __restrict__ bn1k_v,
    const float* __restrict__ dec2_W,
    _Float16* __restrict__ W1fT, _Float16* __restrict__ W2T,
    float* __restrict__ bs)
{
    int t = threadIdx.x;
    if (blockIdx.x < 64) {
        // ---- embed fold, dec1_W[192:392] tile in LDS ----
        __shared__ float A[EMB * 16];
        int h0 = blockIdx.x * 16;
        for (int idx = t; idx < EMB * 16; idx += 256) {
            int j = idx >> 4, hh = idx & 15;
            A[idx] = dec1_W[(size_t)(192 + j) * HID + h0 + hh];
        }
        __syncthreads();
        int hh = t & 15;
        int h = h0 + hh;
        float sc = rsqrtf(bn1k_v[h] + EPSV) * bn1k_g[h];
        for (int e = t >> 4; e < 35; e += 16) {
            float acc = 0.f;
            for (int j = 0; j < EMB; ++j)
                acc = fmaf(obj_embed_W[e * EMB + j], A[j * 16 + hh], acc);
            W1fT[(size_t)h * KP + 192 + e] = (_Float16)(acc * sc);
        }
    } else if (blockIdx.x < 64 + 1536) {
        // ---- W1fT copy, k-major: coalesced dec1_W reads ----
        int idx = (blockIdx.x - 64) * 256 + t;        // 0 .. 393215
        int k = idx >> 10, h = idx & 1023;
        if (k >= 192 && k < 227) return;              // embed region
        float sc = rsqrtf(bn1k_v[h] + EPSV) * bn1k_g[h];
        float v;
        if (k < 192) v = dec1_W[(size_t)k * HID + h];
        else if (k < 355) v = dec1_W[(size_t)(k - 227 + 392) * HID + h];
        else v = 0.f;
        W1fT[(size_t)h * KP + k] = (_Float16)(v * sc);
        if (k == 0) bs[h] = (dec1_b[h] - bn1k_m[h]) * sc + bn1k_b[h];
    } else {
        // ---- W2T ----
        int j = (blockIdx.x - 1600) * 256 + t;        // 0 .. 49151
        int c = j / W2KP, h2 = j % W2KP;
        float v = (c < NCLS) ? dec2_W[(size_t)h2 * NCLS + c] : 0.f;
        W2T[j] = (_Float16)v;
    }
}

// ---------------- main fused kernel: 64 rows/block, 512 threads (8 waves), fp16 MFMA ----
// hidden chunks of 256 -> C[2][4] (32 VGPR acc) -> no spills at 4 waves/SIMD
__global__ __launch_bounds__(512, 4) void k_main(
    const float* __restrict__ distribution, const float* __restrict__ features,
    const float* __restrict__ boxes,
    const float* __restrict__ bn4_g, const float* __restrict__ bn4_b,
    const float* __restrict__ bn4_m, const float* __restrict__ bn4_v,
    const float* __restrict__ pos_W, const float* __restrict__ pos_b,
    const _Float16* __restrict__ W1fT, const _Float16* __restrict__ W2T,
    const float* __restrict__ bs, const float* __restrict__ dec2_b,
    float* __restrict__ out)
{
    extern __shared__ __align__(16) char smem[];
    _Float16* Xs = (_Float16*)smem;                 // 64*392 fp16 = 50176 B
    _Float16* Gc = (_Float16*)(smem + 50176);       // 64*136 fp16 = 17408 B
    float* LstA  = (float*)smem;                    // aliases Xs (dead after GEMM1)
    float* LstB  = LstA + 64 * LSTR;

    int t = threadIdx.x;
    int row0 = blockIdx.x * PER;

    // ---- stage X = [features | distribution | pos] as fp16, K padded to 384 ----
    {
        int r = t >> 3;            // 0..63 local row
        int ko = t & 7;            // k octant (48 each)
        int grow = row0 + r;
        const float* bx = boxes + (size_t)grow * 5;
        float x1 = bx[1], y1 = bx[2], x2 = bx[3], y2 = bx[4];
        float w = x2 - x1 + 1.f, hh = y2 - y1 + 1.f;
        float cs[4] = {x1 + 0.5f * w, y1 + 0.5f * hh, w, hh};
        float hv[4];
#pragma unroll
        for (int i = 0; i < 4; i++)
            hv[i] = (cs[i] - bn4_m[i]) * rsqrtf(bn4_v[i] + EPSV) * bn4_g[i] + bn4_b[i];
        for (int jb = 0; jb < 6; ++jb) {
            int kb = ko * 48 + jb * 8;
            f16x8 v8;
#pragma unroll
            for (int e = 0; e < 8; ++e) {
                int k = kb + e;
                float v;
                if (k < 192) v = features[(size_t)grow * OBJ_DIM + k];
                else if (k < 227) v = distribution[(size_t)grow * (NCLS - 1) + (k - 192)];
                else if (k < 355) {
                    int j = k - 227;
                    float p = pos_b[j];
                    p = fmaf(hv[0], pos_W[j], p);
                    p = fmaf(hv[1], pos_W[POSD + j], p);
                    p = fmaf(hv[2], pos_W[2 * POSD + j], p);
                    p = fmaf(hv[3], pos_W[3 * POSD + j], p);
                    v = fmaxf(p, 0.f);
                } else v = 0.f;
                v8[e] = (_Float16)v;
            }
            *(f16x8*)&Xs[r * XSTR + kb] = v8;
        }
    }
    __syncthreads();

    int wv = t >> 6, lane = t & 63, lr = lane & 15, lq = lane >> 4;
    int rg = wv & 3, kh = wv >> 2;     // GEMM2: row-group, K-half

    f32x4 Lg[3];                       // logit frags: rows 16rg..+15 x classes 48 (K-half kh)
#pragma unroll
    for (int n = 0; n < 3; n++) Lg[n] = (f32x4){0.f, 0.f, 0.f, 0.f};

    for (int c0 = 0; c0 < 4; ++c0) {   // hidden chunks of 256
        int H0 = c0 * 256;
        f32x4 C[2][4];
#pragma unroll
        for (int j = 0; j < 2; j++)
#pragma unroll
            for (int n = 0; n < 4; n++) C[j][n] = (f32x4){0.f, 0.f, 0.f, 0.f};

        // ---- GEMM1 K-loop (A=W1fT hidden rows, B=Xs rows); no barriers ----
        for (int ks = 0; ks < 12; ++ks) {
            int k0 = ks * 32 + lq * 8;
            f16x8 ah[2], bh[4];
#pragma unroll
            for (int j = 0; j < 2; j++)
                ah[j] = *(const f16x8*)(W1fT + (size_t)(H0 + 16 * (wv + 8 * j) + lr) * KP + k0);
#pragma unroll
            for (int n = 0; n < 4; n++)
                bh[n] = *(const f16x8*)&Xs[(16 * n + lr) * XSTR + k0];
#pragma unroll
            for (int j = 0; j < 2; j++)
#pragma unroll
                for (int n = 0; n < 4; n++)
                    C[j][n] = __builtin_amdgcn_mfma_f32_16x16x32_f16(ah[j], bh[n], C[j][n], 0, 0, 0);
        }

        // ---- transform + GEMM2, 2 sub-rounds of 128 hidden (8 waves x 16) ----
        for (int j = 0; j < 2; ++j) {
            __syncthreads();           // Gc free (previous sub-round's GEMM2 done)
            int hb = H0 + 128 * j + 16 * wv + 4 * lq;
            f32x4 bsv = *(const f32x4*)(bs + hb);
#pragma unroll
            for (int n = 0; n < 4; n++) {
                f16x4 g4;
#pragma unroll
                for (int e = 0; e < 4; ++e)
                    g4[e] = (_Float16)fmaxf(C[j][n][e] + bsv[e], 0.f);
                *(f16x4*)&Gc[(16 * n + lr) * GCSTR + 16 * wv + 4 * lq] = g4;
            }
            __syncthreads();           // Gc filled
#pragma unroll
            for (int ks2 = 0; ks2 < 2; ++ks2) {
                int kloc = kh * 64 + ks2 * 32 + lq * 8;
                f16x8 a2 = *(const f16x8*)&Gc[(16 * rg + lr) * GCSTR + kloc];
                int hg = H0 + 128 * j + kloc;
#pragma unroll
                for (int n = 0; n < 3; n++) {
                    f16x8 b2 = *(const f16x8*)(W2T + (size_t)(16 * n + lr) * W2KP + hg);
                    Lg[n] = __builtin_amdgcn_mfma_f32_16x16x32_f16(a2, b2, Lg[n], 0, 0, 0);
                }
            }
        }
    }

    // ---- stash logits: two K-half buffers (alias dead Xs region) ----
    float* myL = kh ? LstB : LstA;
#pragma unroll
    for (int n = 0; n < 3; n++)
#pragma unroll
        for (int e = 0; e < 4; ++e)
            myL[(16 * rg + 4 * lq + e) * LSTR + 16 * n + lr] = Lg[n][e];
    __syncthreads();

    // ---- softmax head + fused per-image human argmax (wave 0) ----
    if (t < 64) {
        int row = row0 + t;
        float lg[36];
#pragma unroll
        for (int c = 1; c < 36; ++c)
            lg[c] = LstA[t * LSTR + c] + LstB[t * LSTR + c] + dec2_b[c];
        float m = lg[1];
#pragma unroll
        for (int c = 2; c < 36; ++c) m = fmaxf(m, lg[c]);
        float d[35];
        float s = 0.f;
#pragma unroll
        for (int c = 1; c < 36; ++c) { float e = expf(lg[c] - m); d[c - 1] = e; s += e; }
        float inv = 1.0f / s;
        float* dout = out + (size_t)row * 35;
#pragma unroll
        for (int j = 0; j < 35; ++j) dout[j] = d[j] * inv;

        // per-row argmax over dist cols 1..34 (first-occurrence), label = distcol+1
        float best = -1.f; int bi = 1;
#pragma unroll
        for (int c = 1; c < 35; ++c) {
            float v = d[c] * inv;
            if (v > best) { best = v; bi = c; }
        }

        // block == image: argmax over dist[:,0] across the 64 lanes
        float v0 = d[0] * inv;
        float mv = v0; int mi = t;
#pragma unroll
        for (int off = 32; off > 0; off >>= 1) {
            float ov = __shfl_down(mv, off);
            int   oi = __shfl_down(mi, off);
            if (ov > mv || (ov == mv && oi < mi)) { mv = ov; mi = oi; }
        }
        int human = __shfl(mi, 0);     // local row of the human
        bool isH = (t == human);
        out[(size_t)NROWS * 35 + row] = isH ? v0 : best;
        out[(size_t)NROWS * 36 + row] = isH ? 1.0f : (float)(bi + 1);
        if (t == 0) out[(size_t)NROWS * 37 + blockIdx.x] = (float)(row0 + human);
    }
}

extern "C" void kernel_launch(void* const* d_in, const int* in_sizes, int n_in,
                              void* d_out, int out_size, void* d_ws, size_t ws_size,
                              hipStream_t stream)
{
    (void)in_sizes; (void)n_in; (void)out_size; (void)ws_size;
    const float* distribution = (const float*)d_in[0];
    const float* features     = (const float*)d_in[1];
    const float* boxes        = (const float*)d_in[2];
    const float* obj_embed_W  = (const float*)d_in[3];
    const float* bn4_g        = (const float*)d_in[4];
    const float* bn4_b        = (const float*)d_in[5];
    const float* bn4_m        = (const float*)d_in[6];
    const float* bn4_v        = (const float*)d_in[7];
    const float* pos_W        = (const float*)d_in[8];
    const float* pos_b        = (const float*)d_in[9];
    const float* dec1_W       = (const float*)d_in[10];
    const float* dec1_b       = (const float*)d_in[11];
    const float* bn1k_g       = (const float*)d_in[12];
    const float* bn1k_b       = (const float*)d_in[13];
    const float* bn1k_m       = (const float*)d_in[14];
    const float* bn1k_v       = (const float*)d_in[15];
    const float* dec2_W       = (const float*)d_in[16];
    const float* dec2_b       = (const float*)d_in[17];

    float* out = (float*)d_out;

    // ws layout (~0.9 MB)
    _Float16* W1fT = (_Float16*)d_ws;                      // 1024*384
    _Float16* W2T  = W1fT + (size_t)HID * KP;              // 48*1024
    float*    bsv  = (float*)(W2T + (size_t)48 * W2KP);    // 1024

    const int LDS_BYTES = 50176 + 17408;                   // 67584
    hipFuncSetAttribute((const void*)k_main,
                        hipFuncAttributeMaxDynamicSharedMemorySize, LDS_BYTES);

    k_prep<<<1792, 256, 0, stream>>>(
        obj_embed_W, dec1_W, dec1_b, bn1k_g, bn1k_b, bn1k_m, bn1k_v, dec2_W,
        W1fT, W2T, bsv);

    k_main<<<BIMG, 512, LDS_BYTES, stream>>>(
        distribution, features, boxes, bn4_g, bn4_b, bn4_m, bn4_v, pos_W, pos_b,
        W1fT, W2T, bsv, dec2_b, out);
}